// Round 10
// baseline (219.338 us; speedup 1.0000x reference)
//
#include <hip/hip_runtime.h>
#include <cfloat>
#include <stdint.h>

#define B_   16
#define N_   2048
#define KK   10          // window = K+1
#define H_   128
#define SUB  16          // chunk size
#define NCH  (N_ / SUB)  // 128 chunks
#define TQ   32          // queries per tile
#define NT   (N_ / TQ)   // 64 tiles per batch

__device__ inline uint32_t f32_ordered(float f) {
    uint32_t u = __float_as_uint(f);
    return (u & 0x80000000u) ? ~u : (u | 0x80000000u);
}

// ---- fused setup: blocks 0..15 bitonic-sort one batch each by x;
//      blocks 16..18 precompute weff/btot.
__global__ __launch_bounds__(1024) void setup_kernel(
    const float* __restrict__ x,
    const float* __restrict__ Wconv, const float* __restrict__ bconv,
    const float* __restrict__ b1,    const float* __restrict__ W2,
    const float* __restrict__ b2,
    float4* __restrict__ xsorted,    // [B][N] (px,py,sm,orig_idx_bits), x-ascending
    float*  __restrict__ weff,       // [H*20]
    float*  __restrict__ btot)       // [H]
{
#pragma clang fp contract(off)
    __shared__ uint64_t sk[N_];
    const int tid = threadIdx.x;
    if (blockIdx.x >= 16) {
        int gid = (blockIdx.x - 16) * 1024 + tid;
        if (gid < H_ * KK * 2) {
            int e = gid / 20, r = gid % 20, k = r >> 1, c = r & 1;
            float acc = 0.f;
            for (int h = 0; h < H_; ++h)
                acc += W2[e * H_ + h] * Wconv[h * (2 * KK) + c * KK + k];
            weff[gid] = acc;
        } else if (gid < H_ * KK * 2 + H_) {
            int e = gid - H_ * KK * 2;
            float acc = b1[e] + b2[e];
            for (int h = 0; h < H_; ++h) acc += W2[e * H_ + h] * bconv[h];
            btot[e] = acc;
        }
        return;
    }
    const int b = blockIdx.x;
    const float2* xb = (const float2*)(x + (size_t)b * N_ * 2);
    for (int i = tid; i < N_; i += 1024)
        sk[i] = ((uint64_t)f32_ordered(xb[i].x) << 32) | (uint32_t)i;
    __syncthreads();
    for (int size = 2; size <= N_; size <<= 1) {
        for (int stride = size >> 1; stride > 0; stride >>= 1) {
            int i = 2 * tid - (tid & (stride - 1));
            int j = i + stride;
            bool up = ((i & size) == 0);
            uint64_t a = sk[i], c = sk[j];
            if (up ? (a > c) : (a < c)) { sk[i] = c; sk[j] = a; }
            __syncthreads();
        }
    }
    for (int i = tid; i < N_; i += 1024) {
        uint32_t idx = (uint32_t)sk[i];
        float2 p = xb[idx];
        float sm = p.x * p.x + p.y * p.y;      // no FMA (np sum convention)
        xsorted[(size_t)b * N_ + i] = make_float4(p.x, p.y, sm, __uint_as_float(idx));
    }
}

// KINIT: d2-field = +inf (guard passes while unfilled), rest all-ones.
#define KINIT ((((uint64_t)0x7F800000u) << 32) | 0xFFFFFFFFull)

// ---- main kernel: 512 threads, tile = 32 queries. lane l: qi = l&31,
// sub = l>>5; wave w's half-waves scan chunk classes w and w+8 (mod 16),
// broadcasting candidates from GLOBAL (L2-resident) to all 32 query-lanes.
// No LDS staging. Seeds = each class's nearest owned chunk: collectively
// the 16 contiguous chunks [2t-7, 2t+8] around the tile.
__global__ __launch_bounds__(512, 6) void knn_conv_kernel(
    const float4* __restrict__ xsorted,
    const float* __restrict__ W1,
    const float* __restrict__ weff,
    const float* __restrict__ btot,
    float* __restrict__ out)
{
#pragma clang fp contract(off)
    __shared__ uint64_t mkeys[TQ * 81];   // 20.7 KB  [q][w*10+j]
    __shared__ float    wcoord[TQ * 21];  //  2.6 KB

    const int tid  = threadIdx.x;
    const int w    = tid >> 6;          // wave 0..7
    const int l    = tid & 63;
    const int qi   = l & 31;            // query within tile
    const int sub  = l >> 5;            // half-wave id
    const int cls  = w + 8 * sub;       // chunk class 0..15
    const int b    = blockIdx.x >> 6;   // grid = 16 * 64
    const int tile = blockIdx.x & 63;

    const float4* xb = xsorted + (size_t)b * N_;
    const int    n  = tile * TQ + qi;
    const float4 qv = xb[n];
    const float  qx = qv.x, qy = qv.y, sqn = qv.z;
    const float  txa = xb[tile * TQ].x;           // tile x-range (uniform)
    const float  txb = xb[tile * TQ + TQ - 1].x;

    uint64_t hk[KK];
#pragma unroll
    for (int j = 0; j < KK; ++j) hk[j] = KINIT;
    float h9f = __uint_as_float(0x7F800000u);   // private 10th-best d2
    float qbm = __uint_as_float(0x7F800000u);   // wave bound + margin

    // broadcast chunk scan: all lanes of a half-wave read the same 16
    // candidates (global, L2-broadcast), each testing its own query.
    auto scan_chunk = [&](int c) {
        const float4* cp = xb + (c << 4);
#pragma unroll
        for (int mm = 0; mm < SUB; ++mm) {
            float4 c4 = cp[mm];
            float s  = sqn + c4.z;
            float pr = qx * c4.x;                        // rn(qx*px)
            float dt = __builtin_fmaf(qy, c4.y, pr);     // fma accumulate (np)
            float d2 = __builtin_fmaf(-2.0f, dt, s);     // rn(s - 2*dot)
            float dc = d2 > 0.0f ? d2 : 0.0f;
            if (dc <= fminf(h9f, qbm)) {
                uint32_t oi = __float_as_uint(c4.w);
                uint64_t key = ((uint64_t)__float_as_uint(dc) << 32)
                             | (oi << 11) | (uint32_t)((c << 4) + mm);
                if (key < hk[KK - 1]) {
#pragma unroll
                    for (int jj = KK - 1; jj >= 1; --jj) {
                        bool cj  = key < hk[jj];
                        bool cjm = key < hk[jj - 1];
                        hk[jj] = cj ? (cjm ? hk[jj - 1] : key) : hk[jj];
                    }
                    hk[0] = (key < hk[0]) ? key : hk[0];
                    h9f = __uint_as_float((uint32_t)(hk[KK - 1] >> 32));
                }
            }
        }
    };

    // seed: nearest owned chunk (== cls mod 16) to tile chunks [A, A+1]
    const int A = 2 * tile;
    const int a = (cls - A) & 15;
    int c1 = A + a, c2 = c1 - 16;
    int cn = (a <= 8) ? c1 : c2;        // dist(c1)=max(0,a-1), dist(c2)=16-a
    if (c1 >= NCH) cn = c2;
    if (c2 < 0 && cn == c2) cn = c1;
    scan_chunk(cn);

    // two-pointer expansion over owned chunks (stride 16). Loop trip is
    // wave-uniform (ballot) so the bound reduction shfls are well-defined;
    // side decisions are half-wave-uniform (tile gaps, per-class pointers).
    int  cl = cn - 16, cr = cn + 16;
    bool la = (cl >= 0), ra = (cr < NCH);
    while (__ballot(la || ra)) {
        // per-query bound: min over this query's 2 classes, then max over
        // the 32 queries. Sound upper bound on each query's true 10th.
        float qb = fminf(h9f, __shfl_xor(h9f, 32, 64));
        qb = fmaxf(qb, __shfl_xor(qb, 1,  64));
        qb = fmaxf(qb, __shfl_xor(qb, 2,  64));
        qb = fmaxf(qb, __shfl_xor(qb, 4,  64));
        qb = fmaxf(qb, __shfl_xor(qb, 8,  64));
        qb = fmaxf(qb, __shfl_xor(qb, 16, 64));
        qbm = qb + 1e-7f;               // margin >> f32 d2 error
        if (la || ra) {
            float gl = la ? fmaxf(0.0f, txa - xb[(cl << 4) + 15].x) : FLT_MAX;
            float gr = ra ? fmaxf(0.0f, xb[cr << 4].x - txb)        : FLT_MAX;
            bool pickL = la && (!ra || gl <= gr);
            if (pickL) {
                if (gl * gl > qbm) la = false;   // gap monotone -> side dead
                else { scan_chunk(cl); cl -= 16; la = (cl >= 0); }
            } else {
                if (gr * gr > qbm) ra = false;
                else { scan_chunk(cr); cr += 16; ra = (cr < NCH); }
            }
        }
    }

    // pair-merge the two classes of each (query, wave) via shfl-32:
    // 10x extract-min; sub==0 lane writes the merged list to mkeys.
    {
        const int mb = qi * 81 + w * 10;
#pragma unroll
        for (int sel = 0; sel < KK; ++sel) {
            uint64_t v = hk[0];
            uint64_t t = __shfl_xor((unsigned long long)v, 32, 64);
            uint64_t m = (t < v) ? t : v;
            if (sub == 0) mkeys[mb + sel] = m;
            if (hk[0] == m) {                   // winner pops (keys unique)
#pragma unroll
                for (int j = 0; j < KK - 1; ++j) hk[j] = hk[j + 1];
                hk[KK - 1] = KINIT;
            }
        }
    }
    __syncthreads();

    // final merge: 8 lanes per query (first 256 threads), shfl-xor{1,2,4}
    // extract-min 10x; designated writer stores window coords (k=9 nearest).
    if (tid < 256) {
        const int q = tid >> 3;
        const int r = tid & 7;
        const int mb = q * 81 + r * 10;
        int p = 0;
#pragma unroll
        for (int sel = 0; sel < KK; ++sel) {
            uint64_t v = (p < KK) ? mkeys[mb + p] : 0xFFFFFFFFFFFFFFFFull;
            uint64_t t1 = __shfl_xor((unsigned long long)v, 1, 64);
            uint64_t m1 = v  < t1 ? v  : t1;
            uint64_t t2 = __shfl_xor((unsigned long long)m1, 2, 64);
            uint64_t m2 = m1 < t2 ? m1 : t2;
            uint64_t t4 = __shfl_xor((unsigned long long)m2, 4, 64);
            uint64_t vm = m2 < t4 ? m2 : t4;
            if (v == vm) {
                ++p;
                float4 c = xb[(int)(vm & 0x7FF)];
                const int k = (KK - 1) - sel;
                wcoord[q * 21 + 2 * k + 0] = c.x;
                wcoord[q * 21 + 2 * k + 1] = c.y;
            }
        }
    }

    // epilogue weights (L2-hot; loaded while merge finishes elsewhere)
    const int e = tid & 127;
    float we[20];
    {
        const float4* wp = (const float4*)(weff + e * 20);
#pragma unroll
        for (int r = 0; r < 5; ++r) {
            float4 v = wp[r];
            we[4 * r + 0] = v.x; we[4 * r + 1] = v.y;
            we[4 * r + 2] = v.z; we[4 * r + 3] = v.w;
        }
    }
    const float w1x = W1[e * 2 + 0];
    const float w1y = W1[e * 2 + 1];
    const float bt  = btot[e];
    __syncthreads();

    // epilogue: thread -> channel e; 32 rows scattered to ORIGINAL indices
    const int qb_ = tid >> 7;
    const size_t obase = (size_t)b * N_ * H_;
#pragma unroll
    for (int jj = 0; jj < 8; ++jj) {
        const int qq = qb_ + 4 * jj;
        float4 xq = xb[tile * TQ + qq];
        uint32_t orig = __float_as_uint(xq.w);
        const float* wc = &wcoord[qq * 21];
        float acc = bt;
        acc += xq.x * w1x;
        acc += xq.y * w1y;
#pragma unroll
        for (int k = 0; k < KK; ++k) {
            acc += wc[2 * k + 0] * we[2 * k + 0];
            acc += wc[2 * k + 1] * we[2 * k + 1];
        }
        out[obase + (size_t)orig * H_ + e] = acc;
    }
}

extern "C" void kernel_launch(void* const* d_in, const int* in_sizes, int n_in,
                              void* d_out, int out_size, void* d_ws, size_t ws_size,
                              hipStream_t stream) {
    const float* x     = (const float*)d_in[0];
    const float* Wconv = (const float*)d_in[1];
    const float* bconv = (const float*)d_in[2];
    const float* W1    = (const float*)d_in[3];
    const float* b1    = (const float*)d_in[4];
    const float* W2    = (const float*)d_in[5];
    const float* b2    = (const float*)d_in[6];
    float* out  = (float*)d_out;
    float* weff = (float*)d_ws;                           // 2560 floats
    float* btot = weff + H_ * KK * 2;                     // 128 floats
    float4* xsorted = (float4*)((char*)d_ws + 16384);     // 16*2048*16B

    setup_kernel<<<dim3(19), dim3(1024), 0, stream>>>(
        x, Wconv, bconv, b1, W2, b2, xsorted, weff, btot);
    knn_conv_kernel<<<dim3(B_ * NT), dim3(512), 0, stream>>>(
        xsorted, W1, weff, btot, out);
}

// Round 11
// 208.624 us; speedup vs baseline: 1.0514x; 1.0514x over previous
//
#include <hip/hip_runtime.h>
#include <cfloat>
#include <stdint.h>

#define B_   16
#define N_   2048
#define KK   10          // window = K+1
#define H_   128
#define SUB  16          // chunk size
#define NCH  (N_ / SUB)  // 128 chunks
#define W_   4           // waves per block = chunk classes (mod 4)
#define CAP  12          // capture buffer depth per (query, class)

__device__ inline uint32_t f32_ordered(float f) {
    uint32_t u = __float_as_uint(f);
    return (u & 0x80000000u) ? ~u : (u | 0x80000000u);
}

// ---- fused setup: blocks 0..15 bitonic-sort one batch each by x;
//      blocks 16..18 precompute weff/btot.
__global__ __launch_bounds__(1024) void setup_kernel(
    const float* __restrict__ x,
    const float* __restrict__ Wconv, const float* __restrict__ bconv,
    const float* __restrict__ b1,    const float* __restrict__ W2,
    const float* __restrict__ b2,
    float4* __restrict__ xsorted,    // [B][N] (px,py,sm,orig_idx_bits), x-ascending
    float*  __restrict__ weff,       // [H*20]
    float*  __restrict__ btot)       // [H]
{
#pragma clang fp contract(off)
    __shared__ uint64_t sk[N_];
    const int tid = threadIdx.x;
    if (blockIdx.x >= 16) {
        int gid = (blockIdx.x - 16) * 1024 + tid;
        if (gid < H_ * KK * 2) {
            int e = gid / 20, r = gid % 20, k = r >> 1, c = r & 1;
            float acc = 0.f;
            for (int h = 0; h < H_; ++h)
                acc += W2[e * H_ + h] * Wconv[h * (2 * KK) + c * KK + k];
            weff[gid] = acc;
        } else if (gid < H_ * KK * 2 + H_) {
            int e = gid - H_ * KK * 2;
            float acc = b1[e] + b2[e];
            for (int h = 0; h < H_; ++h) acc += W2[e * H_ + h] * bconv[h];
            btot[e] = acc;
        }
        return;
    }
    const int b = blockIdx.x;
    const float2* xb = (const float2*)(x + (size_t)b * N_ * 2);
    for (int i = tid; i < N_; i += 1024)
        sk[i] = ((uint64_t)f32_ordered(xb[i].x) << 32) | (uint32_t)i;
    __syncthreads();
    for (int size = 2; size <= N_; size <<= 1) {
        for (int stride = size >> 1; stride > 0; stride >>= 1) {
            int i = 2 * tid - (tid & (stride - 1));
            int j = i + stride;
            bool up = ((i & size) == 0);
            uint64_t a = sk[i], c = sk[j];
            if (up ? (a > c) : (a < c)) { sk[i] = c; sk[j] = a; }
            __syncthreads();
        }
    }
    for (int i = tid; i < N_; i += 1024) {
        uint32_t idx = (uint32_t)sk[i];
        float2 p = xb[idx];
        float sm = p.x * p.x + p.y * p.y;      // no FMA (np sum convention)
        xsorted[(size_t)b * N_ + i] = make_float4(p.x, p.y, sm, __uint_as_float(idx));
    }
}

#define KINIT 0xFFFFFFFFFFFFFFFFull

// ---- main kernel: 256 threads = 4 waves per 64-query tile. Wave w owns
// chunks == w (mod 4). Pass 1: distance-only top-10 via branchless med3
// insert (2 ops/slot, unconditional) + two-pointer window expansion.
// Pass 2: rescan window, capture dc<=tau into per-lane LDS buffers.
// Then: 12-elem local u64 sort -> 4-list merge -> coords -> epilogue.
__global__ __launch_bounds__(256, 4) void knn_conv_kernel(
    const float4* __restrict__ xsorted,
    const float* __restrict__ W1,
    const float* __restrict__ weff,
    const float* __restrict__ btot,
    float* __restrict__ out)
{
#pragma clang fp contract(off)
    __shared__ uint64_t cap[W_ * 64 * 13];   // 26.6 KB: capture bufs / final lists
    __shared__ uint32_t poslist[64 * KK];    //  2.5 KB
    __shared__ float    wcoord[64 * 21];     //  5.25 KB

    const int tid  = threadIdx.x;
    const int w    = tid >> 6;          // chunk class 0..3
    const int qi   = tid & 63;          // query within tile
    const int b    = blockIdx.x >> 5;   // grid = 16 * 32
    const int tile = blockIdx.x & 31;

    const float4* xb = xsorted + (size_t)b * N_;
    const int    n  = tile * 64 + qi;
    const float4 qv = xb[n];
    const float  qx = qv.x, qy = qv.y, sqn = qv.z;
    const float  txa = xb[tile * 64].x;        // tile x-range (uniform)
    const float  txb = xb[tile * 64 + 63].x;

    // pass 1: distances only. Branchless sorted insert:
    // new[0]=min(v,hd[0]); new[j]=max(hd[j-1], min(v,hd[j])) (= med3).
    // Unconditional is correct: if v >= hd[9] nothing changes.
    float hd[KK];
#pragma unroll
    for (int j = 0; j < KK; ++j) hd[j] = FLT_MAX;

    auto dist = [&](float4 c4) -> float {
        float s  = sqn + c4.z;
        float pr = qx * c4.x;                        // rn(qx*px)
        float dt = __builtin_fmaf(qy, c4.y, pr);     // fma accumulate (np)
        float d2 = __builtin_fmaf(-2.0f, dt, s);     // rn(s - 2*dot)
        return d2 > 0.0f ? d2 : 0.0f;
    };

    auto scan1 = [&](int c) {
        const float4* cp = xb + (c << 4);
#pragma unroll
        for (int mm = 0; mm < SUB; ++mm) {
            float v = dist(cp[mm]);
            float prev = hd[0];
            hd[0] = fminf(v, hd[0]);
#pragma unroll
            for (int j = 1; j < KK; ++j) {
                float cur = hd[j];
                hd[j] = fmaxf(prev, fminf(v, cur));
                prev = cur;
            }
        }
    };

    // seed: the in-tile chunk of this class (tile spans chunks [4t, 4t+3])
    const int c0 = 4 * tile + w;
    scan1(c0);
    int clo = c0, chi = c0;

    // two-pointer expansion (stride 4 = class). Wave-uniform control.
    int  cl = c0 - 4, cr = c0 + 4;
    bool la = (cl >= 0), ra = (cr < NCH);
    while (la || ra) {
        float wm = hd[KK - 1];                 // wave-max of per-query 10th
        wm = fmaxf(wm, __shfl_xor(wm, 1,  64));
        wm = fmaxf(wm, __shfl_xor(wm, 2,  64));
        wm = fmaxf(wm, __shfl_xor(wm, 4,  64));
        wm = fmaxf(wm, __shfl_xor(wm, 8,  64));
        wm = fmaxf(wm, __shfl_xor(wm, 16, 64));
        wm = fmaxf(wm, __shfl_xor(wm, 32, 64));
        float gl = la ? fmaxf(0.0f, txa - xb[(cl << 4) + 15].x) : FLT_MAX;
        float gr = ra ? fmaxf(0.0f, xb[cr << 4].x - txb)        : FLT_MAX;
        bool pickL = la && (!ra || gl <= gr);
        if (pickL) {
            // margin 4e-6 covers f32 rounding of the reference d2 form
            if (gl * gl - 4e-6f > wm) la = false;
            else { scan1(cl); clo = cl; cl -= 4; la = (cl >= 0); }
        } else {
            if (gr * gr - 4e-6f > wm) ra = false;
            else { scan1(cr); chi = cr; cr += 4; ra = (cr < NCH); }
        }
    }

    const float tau = hd[KK - 1];   // exact 10th-smallest d2 of this class

    // pass 2: rescan [clo, chi] (same candidates, same arithmetic -> dc is
    // bit-equal), capture dc <= tau. Each class holds >=10 such (tau is its
    // own 10th), and every global-top-10 member satisfies dc <= global 10th
    // <= tau of its class -> captures cover the answer.
    const int cb = (w * 64 + qi) * 13;
#pragma unroll
    for (int i = 0; i < CAP; ++i) cap[cb + i] = KINIT;
    int cnt = 0;
    for (int c = clo; c <= chi; c += 4) {
        const float4* cp = xb + (c << 4);
#pragma unroll
        for (int mm = 0; mm < SUB; ++mm) {
            float4 c4 = cp[mm];
            float v = dist(c4);
            if (v <= tau) {
                if (cnt < CAP) {
                    uint32_t oi = __float_as_uint(c4.w);
                    uint64_t key = ((uint64_t)__float_as_uint(v) << 32)
                                 | (oi << 11) | (uint32_t)((c << 4) + mm);
                    cap[cb + cnt] = key;
                }
                ++cnt;
            }
        }
    }

    // local sort: 12 entries -> sorted top-10 u64 (exact (d2, origidx) order;
    // KINIT padding sinks). All lanes active -> no wave-any waste.
    uint64_t hk[KK];
#pragma unroll
    for (int j = 0; j < KK; ++j) hk[j] = KINIT;
#pragma unroll
    for (int i = 0; i < CAP; ++i) {
        uint64_t key = cap[cb + i];
        if (key < hk[KK - 1]) {
#pragma unroll
            for (int j = KK - 1; j >= 1; --j) {
                bool cj  = key < hk[j];
                bool cjm = key < hk[j - 1];
                hk[j] = cj ? (cjm ? hk[j - 1] : key) : hk[j];
            }
            hk[0] = (key < hk[0]) ? key : hk[0];
        }
    }
#pragma unroll
    for (int j = 0; j < KK; ++j) cap[cb + j] = hk[j];   // final list (aliased)
    __syncthreads();

    // merge 4 sorted lists per query: 4 lanes/query (q = tid>>2, r = tid&3),
    // extract-min 10x via quad shfl. Keys unique (pos field).
    {
        const int q = tid >> 2;
        const int r = tid & 3;
        int p = 0;
#pragma unroll
        for (int sel = 0; sel < KK; ++sel) {
            uint64_t v = (p < KK) ? cap[(r * 64 + q) * 13 + p] : KINIT;
            uint64_t t;
            t = __shfl_xor((unsigned long long)v, 1, 64); v = (t < v) ? t : v;
            uint64_t vm = v;
            t = __shfl_xor((unsigned long long)vm, 2, 64); vm = (t < vm) ? t : vm;
            // recompute own head for winner test
            uint64_t own = (p < KK) ? cap[(r * 64 + q) * 13 + p] : KINIT;
            if (r == 0) poslist[q * KK + sel] = (uint32_t)(vm & 0x7FF);
            if (own == vm) ++p;
        }
    }
    __syncthreads();

    // gather winner coordinates: 640 entries cooperatively
    for (int i = tid; i < 64 * KK; i += 256) {
        int q   = i / KK;
        int sel = i - q * KK;
        float4 c4 = xb[poslist[i]];
        wcoord[q * 21 + 2 * (KK - 1 - sel) + 0] = c4.x;  // nearest -> k=9
        wcoord[q * 21 + 2 * (KK - 1 - sel) + 1] = c4.y;
    }

    // epilogue weights (L2-hot)
    const int e = tid & 127;
    float we[20];
    {
        const float4* wp = (const float4*)(weff + e * 20);
#pragma unroll
        for (int r = 0; r < 5; ++r) {
            float4 v = wp[r];
            we[4 * r + 0] = v.x; we[4 * r + 1] = v.y;
            we[4 * r + 2] = v.z; we[4 * r + 3] = v.w;
        }
    }
    const float w1x = W1[e * 2 + 0];
    const float w1y = W1[e * 2 + 1];
    const float bt  = btot[e];
    __syncthreads();

    // epilogue: thread -> channel e; 64 rows scattered to ORIGINAL indices
    // (per wave: 64 consecutive channels -> coalesced store).
    const int half = tid >> 7;
    const size_t obase = (size_t)b * N_ * H_;
#pragma unroll 4
    for (int jj = 0; jj < 32; ++jj) {
        const int qq = half + 2 * jj;
        float4 xq = xb[tile * 64 + qq];
        uint32_t orig = __float_as_uint(xq.w);
        const float* wc = &wcoord[qq * 21];
        float acc = bt;
        acc += xq.x * w1x;
        acc += xq.y * w1y;
#pragma unroll
        for (int k = 0; k < KK; ++k) {
            acc += wc[2 * k + 0] * we[2 * k + 0];
            acc += wc[2 * k + 1] * we[2 * k + 1];
        }
        out[obase + (size_t)orig * H_ + e] = acc;
    }
}

extern "C" void kernel_launch(void* const* d_in, const int* in_sizes, int n_in,
                              void* d_out, int out_size, void* d_ws, size_t ws_size,
                              hipStream_t stream) {
    const float* x     = (const float*)d_in[0];
    const float* Wconv = (const float*)d_in[1];
    const float* bconv = (const float*)d_in[2];
    const float* W1    = (const float*)d_in[3];
    const float* b1    = (const float*)d_in[4];
    const float* W2    = (const float*)d_in[5];
    const float* b2    = (const float*)d_in[6];
    float* out  = (float*)d_out;
    float* weff = (float*)d_ws;                           // 2560 floats
    float* btot = weff + H_ * KK * 2;                     // 128 floats
    float4* xsorted = (float4*)((char*)d_ws + 16384);     // 16*2048*16B

    setup_kernel<<<dim3(19), dim3(1024), 0, stream>>>(
        x, Wconv, bconv, b1, W2, b2, xsorted, weff, btot);
    knn_conv_kernel<<<dim3(B_ * 32), dim3(256), 0, stream>>>(
        xsorted, W1, weff, btot, out);
}

// Round 12
// 180.482 us; speedup vs baseline: 1.2153x; 1.1559x over previous
//
#include <hip/hip_runtime.h>
#include <cfloat>
#include <stdint.h>

#define B_   16
#define N_   2048
#define KK   10          // window = K+1
#define H_   128
#define SUB  16          // chunk size
#define NCH  (N_ / SUB)  // 128 chunks
#define W_   8           // waves per block = chunk classes (mod 8)
#define CAP  12          // capture depth per (class, query)

__device__ inline uint32_t f32_ordered(float f) {
    uint32_t u = __float_as_uint(f);
    return (u & 0x80000000u) ? ~u : (u | 0x80000000u);
}

// ---- fused setup: blocks 0..15 bitonic-sort one batch each by x;
//      blocks 16..18 precompute weff/btot.
__global__ __launch_bounds__(1024) void setup_kernel(
    const float* __restrict__ x,
    const float* __restrict__ Wconv, const float* __restrict__ bconv,
    const float* __restrict__ b1,    const float* __restrict__ W2,
    const float* __restrict__ b2,
    float4* __restrict__ xsorted,    // [B][N] (px,py,sm,orig_idx_bits), x-ascending
    float*  __restrict__ weff,       // [H*20]
    float*  __restrict__ btot)       // [H]
{
#pragma clang fp contract(off)
    __shared__ uint64_t sk[N_];
    const int tid = threadIdx.x;
    if (blockIdx.x >= 16) {
        int gid = (blockIdx.x - 16) * 1024 + tid;
        if (gid < H_ * KK * 2) {
            int e = gid / 20, r = gid % 20, k = r >> 1, c = r & 1;
            float acc = 0.f;
            for (int h = 0; h < H_; ++h)
                acc += W2[e * H_ + h] * Wconv[h * (2 * KK) + c * KK + k];
            weff[gid] = acc;
        } else if (gid < H_ * KK * 2 + H_) {
            int e = gid - H_ * KK * 2;
            float acc = b1[e] + b2[e];
            for (int h = 0; h < H_; ++h) acc += W2[e * H_ + h] * bconv[h];
            btot[e] = acc;
        }
        return;
    }
    const int b = blockIdx.x;
    const float2* xb = (const float2*)(x + (size_t)b * N_ * 2);
    for (int i = tid; i < N_; i += 1024)
        sk[i] = ((uint64_t)f32_ordered(xb[i].x) << 32) | (uint32_t)i;
    __syncthreads();
    for (int size = 2; size <= N_; size <<= 1) {
        for (int stride = size >> 1; stride > 0; stride >>= 1) {
            int i = 2 * tid - (tid & (stride - 1));
            int j = i + stride;
            bool up = ((i & size) == 0);
            uint64_t a = sk[i], c = sk[j];
            if (up ? (a > c) : (a < c)) { sk[i] = c; sk[j] = a; }
            __syncthreads();
        }
    }
    for (int i = tid; i < N_; i += 1024) {
        uint32_t idx = (uint32_t)sk[i];
        float2 p = xb[idx];
        float sm = p.x * p.x + p.y * p.y;      // no FMA (np sum convention)
        xsorted[(size_t)b * N_ + i] = make_float4(p.x, p.y, sm, __uint_as_float(idx));
    }
}

#define KINIT 0xFFFFFFFFFFFFFFFFull

// ---- main kernel: 512 thr = 8 waves per 64-query tile; wave w = chunk
// class (mod 8), lane = query. Pass 1: med3 distance-only top-10 with a
// CROSS-CLASS shared per-query bound (LDS atomicMin). Pass 2: rescan own
// range, capture dc <= tau* (final shared bound). Sort + 8-way merge.
__global__ __launch_bounds__(512, 4) void knn_conv_kernel(
    const float4* __restrict__ xsorted,
    const float* __restrict__ W1,
    const float* __restrict__ weff,
    const float* __restrict__ btot,
    float* __restrict__ out)
{
#pragma clang fp contract(off)
    __shared__ uint64_t cap[W_ * 64 * 13];   // 53.2 KB capture/final lists
    __shared__ uint32_t poslist[64 * KK];    //  2.5 KB
    __shared__ float    wcoord[64 * 21];     //  5.25 KB
    volatile __shared__ uint32_t stau[64];   //  256 B shared per-query bound

    const int tid  = threadIdx.x;
    const int w    = tid >> 6;          // chunk class 0..7
    const int qi   = tid & 63;          // query within tile
    const int b    = blockIdx.x >> 5;   // grid = 16 * 32
    const int tile = blockIdx.x & 31;

    if (tid < 64) stau[tid] = 0xFFFFFFFFu;
    __syncthreads();

    const float4* xb = xsorted + (size_t)b * N_;
    const int    n  = tile * 64 + qi;
    const float4 qv = xb[n];
    const float  qx = qv.x, qy = qv.y, sqn = qv.z;
    const float  txa = xb[tile * 64].x;        // tile x-range (uniform)
    const float  txb = xb[tile * 64 + 63].x;

    auto dist = [&](float4 c4) -> float {
        float s  = sqn + c4.z;
        float pr = qx * c4.x;                        // rn(qx*px)
        float dt = __builtin_fmaf(qy, c4.y, pr);     // fma accumulate (np)
        float d2 = __builtin_fmaf(-2.0f, dt, s);     // rn(s - 2*dot)
        return d2 > 0.0f ? d2 : 0.0f;
    };

    // pass 1: distance-only top-10, branchless med3 insert (unconditional)
    float hd[KK];
#pragma unroll
    for (int j = 0; j < KK; ++j) hd[j] = FLT_MAX;

    auto scan1 = [&](int c) {
        const float4* cp = xb + (c << 4);
#pragma unroll
        for (int mm = 0; mm < SUB; ++mm) {
            float v = dist(cp[mm]);
            float prev = hd[0];
            hd[0] = fminf(v, hd[0]);
#pragma unroll
            for (int j = 1; j < KK; ++j) {
                float cur = hd[j];
                hd[j] = fmaxf(prev, fminf(v, cur));
                prev = cur;
            }
        }
    };

    // seed: nearest chunk == w (mod 8) to tile chunks [A, A+3]
    const int A = 4 * tile;
    const int a = (w - A) & 7;
    int cn = A + a;
    if (a > 5) cn -= 8;
    if (cn >= NCH) cn -= 8;
    if (cn < 0) cn += 8;
    scan1(cn);
    atomicMin((uint32_t*)&stau[qi], __float_as_uint(hd[KK - 1]));

    int clo = cn, chi = cn;
    int  cl = cn - 8, cr = cn + 8;
    bool la = (cl >= 0), ra = (cr < NCH);
    while (la || ra) {
        // shared per-query bound (monotone decreasing -> stale reads sound),
        // wave-max over the 64 queries; margin >> f32 d2/gap rounding.
        float tb = __uint_as_float(stau[qi]);
        tb = fmaxf(tb, __shfl_xor(tb, 1,  64));
        tb = fmaxf(tb, __shfl_xor(tb, 2,  64));
        tb = fmaxf(tb, __shfl_xor(tb, 4,  64));
        tb = fmaxf(tb, __shfl_xor(tb, 8,  64));
        tb = fmaxf(tb, __shfl_xor(tb, 16, 64));
        tb = fmaxf(tb, __shfl_xor(tb, 32, 64));
        const float bound = tb + 4e-6f;
        float gl = la ? fmaxf(0.0f, txa - xb[(cl << 4) + 15].x) : FLT_MAX;
        float gr = ra ? fmaxf(0.0f, xb[cr << 4].x - txb)        : FLT_MAX;
        bool pickL = la && (!ra || gl <= gr);
        if (pickL) {
            if (gl * gl > bound) la = false;       // gap monotone -> side dead
            else {
                scan1(cl); clo = cl; cl -= 8; la = (cl >= 0);
                atomicMin((uint32_t*)&stau[qi], __float_as_uint(hd[KK - 1]));
            }
        } else {
            if (gr * gr > bound) ra = false;
            else {
                scan1(cr); chi = cr; cr += 8; ra = (cr < NCH);
                atomicMin((uint32_t*)&stau[qi], __float_as_uint(hd[KK - 1]));
            }
        }
    }
    __syncthreads();                    // stau now final

    // pass 2: rescan own range with tau* (bit-identical dist); capture
    // dc <= tau*. tau* <= own class tau -> <= ~10 captures per class.
    const float tau = __uint_as_float(stau[qi]);
    const int cb = (w * 64 + qi) * 13;
    int cnt = 0;
    for (int c = clo; c <= chi; c += 8) {
        const float4* cp = xb + (c << 4);
#pragma unroll
        for (int mm = 0; mm < SUB; ++mm) {
            float4 c4 = cp[mm];
            float v = dist(c4);
            if (v <= tau && cnt < CAP) {
                uint32_t oi = __float_as_uint(c4.w);
                cap[cb + cnt] = ((uint64_t)__float_as_uint(v) << 32)
                              | (oi << 11) | (uint32_t)((c << 4) + mm);
                ++cnt;
            }
        }
    }
    for (int i = cnt; i < CAP; ++i) cap[cb + i] = KINIT;

    // per-lane sort of own capture buffer -> sorted top-10 u64
    {
        uint64_t hk[KK];
#pragma unroll
        for (int j = 0; j < KK; ++j) hk[j] = KINIT;
#pragma unroll
        for (int i = 0; i < CAP; ++i) {
            uint64_t key = cap[cb + i];
            if (key < hk[KK - 1]) {
#pragma unroll
                for (int j = KK - 1; j >= 1; --j) {
                    bool cj  = key < hk[j];
                    bool cjm = key < hk[j - 1];
                    hk[j] = cj ? (cjm ? hk[j - 1] : key) : hk[j];
                }
                hk[0] = (key < hk[0]) ? key : hk[0];
            }
        }
#pragma unroll
        for (int j = 0; j < KK; ++j) cap[cb + j] = hk[j];
    }
    __syncthreads();

    // merge 8 sorted lists per query: 8 lanes/query (q = tid>>3, r = tid&7),
    // groups of 8 aligned in-wave -> shfl_xor 1/2/4 stay in-group.
    {
        const int q = tid >> 3;
        const int r = tid & 7;
        const int mb = (r * 64 + q) * 13;
        int p = 0;
#pragma unroll
        for (int sel = 0; sel < KK; ++sel) {
            uint64_t own = (p < KK) ? cap[mb + p] : KINIT;
            uint64_t v = own, t;
            t = __shfl_xor((unsigned long long)v, 1, 64); v = (t < v) ? t : v;
            t = __shfl_xor((unsigned long long)v, 2, 64); v = (t < v) ? t : v;
            t = __shfl_xor((unsigned long long)v, 4, 64); v = (t < v) ? t : v;
            if (r == 0) poslist[q * KK + sel] = (uint32_t)(v & 0x7FF);
            if (own == v) ++p;          // keys unique (pos field)
        }
    }
    __syncthreads();

    // gather winner coordinates (640 entries, cooperative)
    for (int i = tid; i < 64 * KK; i += 512) {
        int q   = i / KK;
        int sel = i - q * KK;
        float4 c4 = xb[poslist[i]];
        wcoord[q * 21 + 2 * (KK - 1 - sel) + 0] = c4.x;  // nearest -> k=9
        wcoord[q * 21 + 2 * (KK - 1 - sel) + 1] = c4.y;
    }

    // epilogue weights (L2-hot; overlap with barrier)
    const int e = tid & 127;
    float we[20];
    {
        const float4* wp = (const float4*)(weff + e * 20);
#pragma unroll
        for (int r = 0; r < 5; ++r) {
            float4 v = wp[r];
            we[4 * r + 0] = v.x; we[4 * r + 1] = v.y;
            we[4 * r + 2] = v.z; we[4 * r + 3] = v.w;
        }
    }
    const float w1x = W1[e * 2 + 0];
    const float w1y = W1[e * 2 + 1];
    const float bt  = btot[e];
    __syncthreads();

    // epilogue: thread -> channel e; 64 rows scattered to ORIGINAL indices
    const int qb_ = tid >> 7;
    const size_t obase = (size_t)b * N_ * H_;
#pragma unroll
    for (int jj = 0; jj < 16; ++jj) {
        const int qq = qb_ + 4 * jj;
        float4 xq = xb[tile * 64 + qq];
        uint32_t orig = __float_as_uint(xq.w);
        const float* wc = &wcoord[qq * 21];
        float acc = bt;
        acc += xq.x * w1x;
        acc += xq.y * w1y;
#pragma unroll
        for (int k = 0; k < KK; ++k) {
            acc += wc[2 * k + 0] * we[2 * k + 0];
            acc += wc[2 * k + 1] * we[2 * k + 1];
        }
        out[obase + (size_t)orig * H_ + e] = acc;
    }
}

extern "C" void kernel_launch(void* const* d_in, const int* in_sizes, int n_in,
                              void* d_out, int out_size, void* d_ws, size_t ws_size,
                              hipStream_t stream) {
    const float* x     = (const float*)d_in[0];
    const float* Wconv = (const float*)d_in[1];
    const float* bconv = (const float*)d_in[2];
    const float* W1    = (const float*)d_in[3];
    const float* b1    = (const float*)d_in[4];
    const float* W2    = (const float*)d_in[5];
    const float* b2    = (const float*)d_in[6];
    float* out  = (float*)d_out;
    float* weff = (float*)d_ws;                           // 2560 floats
    float* btot = weff + H_ * KK * 2;                     // 128 floats
    float4* xsorted = (float4*)((char*)d_ws + 16384);     // 16*2048*16B

    setup_kernel<<<dim3(19), dim3(1024), 0, stream>>>(
        x, Wconv, bconv, b1, W2, b2, xsorted, weff, btot);
    knn_conv_kernel<<<dim3(B_ * 32), dim3(512), 0, stream>>>(
        xsorted, W1, weff, btot, out);
}